// Round 1
// baseline (8288.341 us; speedup 1.0000x reference)
//
#include <hip/hip_runtime.h>
#include <hip/hip_bf16.h>

// WindowAttention: B=8, H=W=256, C=96, ws=8, heads=4, hd=24.
// 8192 windows of 64 tokens. Fully fused fp32 kernel, one block per window.

#define NWIN 8192
#define C96 96
#define NH 4
#define HD 24
#define XS_STRIDE 100   // 96 + 4 pad (breaks 96 % 32 == 0 bank alias)
#define QS_STRIDE 76    // 72 + 4 pad

__global__ void winattn_kernel(const float* __restrict__ x,
                               const float* __restrict__ qkv_w,
                               const float* __restrict__ qkv_b,
                               const float* __restrict__ proj_w,
                               const float* __restrict__ proj_b,
                               float* __restrict__ out) {
    __shared__ float xs[64 * XS_STRIDE];   // x window [64][96] (stride 100)
    __shared__ float buf[64 * XS_STRIDE];  // qkv head [64][72] (stride 76), later out staging (stride 100)

    const int wid = blockIdx.x;
    const int b  = wid >> 10;          // / (32*32)
    const int wh = (wid >> 5) & 31;
    const int ww = wid & 31;
    const int tid = threadIdx.x;

    // float index of window's (r=0,c=0) pixel, channel 0
    const size_t win_base = ((size_t)(b * 256 + wh * 8) * 256 + (size_t)(ww * 8)) * C96;

    // ---- load x window: 64 tokens x 24 float4
    for (int i = tid; i < 64 * 24; i += 256) {
        const int t  = i / 24;
        const int q4 = i - t * 24;
        const int r  = t >> 3, cc = t & 7;
        const float4 v = *(const float4*)(x + win_base + ((size_t)r * 256 + cc) * C96 + q4 * 4);
        *(float4*)&xs[t * XS_STRIDE + q4 * 4] = v;
    }
    __syncthreads();

    const int t = tid >> 2;   // token 0..63
    const int g = tid & 3;    // lane-in-row 0..3

    const float scale = 0.20412414523193154f;  // 24^-0.5

    float oacc[24];           // proj accumulators: out[t][c], c = g + 4*m
    #pragma unroll
    for (int m = 0; m < 24; ++m) oacc[m] = 0.f;

    for (int h = 0; h < NH; ++h) {
        // ======== QKV for head h: j_local = g + 4*m (m=0..17), s = m/6 (q/k/v), d = g + 4*(m%6)
        {
            float acc[18];
            #pragma unroll
            for (int m = 0; m < 18; ++m) acc[m] = 0.f;

            for (int c0 = 0; c0 < 96; c0 += 4) {
                const float4 xv = *(const float4*)&xs[t * XS_STRIDE + c0];
                #pragma unroll
                for (int m = 0; m < 18; ++m) {
                    const int s = m / 6;                 // compile-time per unrolled m
                    const int d = g + 4 * (m - s * 6);
                    const int row = s * 96 + h * 24 + d;
                    const float4 wv = *(const float4*)(qkv_w + row * 96 + c0);
                    acc[m] += xv.x * wv.x + xv.y * wv.y + xv.z * wv.z + xv.w * wv.w;
                }
            }
            #pragma unroll
            for (int m = 0; m < 18; ++m) {
                const int s = m / 6;
                const int d = g + 4 * (m - s * 6);
                const int jl = s * 24 + d;               // 0..71 within head buffer
                buf[t * QS_STRIDE + jl] = acc[m] + qkv_b[s * 96 + h * 24 + d];
            }
        }
        __syncthreads();

        // ======== logits S[t][u], u = 4*ul + g (keeps 4 lanes on distinct banks)
        float p[16];
        float mymax = -1e30f;
        #pragma unroll
        for (int ul = 0; ul < 16; ++ul) {
            const int u = 4 * ul + g;
            float s = 0.f;
            #pragma unroll
            for (int d = 0; d < 24; d += 4) {
                const float4 qv = *(const float4*)&buf[t * QS_STRIDE + d];
                const float4 kv = *(const float4*)&buf[u * QS_STRIDE + 24 + d];
                s += qv.x * kv.x + qv.y * kv.y + qv.z * kv.z + qv.w * kv.w;
            }
            p[ul] = s * scale;
            mymax = fmaxf(mymax, p[ul]);
        }
        // softmax over the 4-lane group (row t)
        mymax = fmaxf(mymax, __shfl_xor(mymax, 1));
        mymax = fmaxf(mymax, __shfl_xor(mymax, 2));
        float mysum = 0.f;
        #pragma unroll
        for (int ul = 0; ul < 16; ++ul) {
            p[ul] = __expf(p[ul] - mymax);
            mysum += p[ul];
        }
        mysum += __shfl_xor(mysum, 1);
        mysum += __shfl_xor(mysum, 2);
        const float rsum = 1.0f / mysum;

        // ======== PV: O[t][d] = (1/sum) * sum_u p[u] * v[u][d]
        float od[24];
        #pragma unroll
        for (int d = 0; d < 24; ++d) od[d] = 0.f;
        #pragma unroll
        for (int ul = 0; ul < 16; ++ul) {
            const int u = 4 * ul + g;
            const float pv = p[ul];
            const float* vb = &buf[u * QS_STRIDE + 48];
            #pragma unroll
            for (int d4 = 0; d4 < 6; ++d4) {
                const float4 vv = *(const float4*)(vb + d4 * 4);
                od[d4 * 4 + 0] += pv * vv.x;
                od[d4 * 4 + 1] += pv * vv.y;
                od[d4 * 4 + 2] += pv * vv.z;
                od[d4 * 4 + 3] += pv * vv.w;
            }
        }
        #pragma unroll
        for (int d = 0; d < 24; ++d) {
            od[d] += __shfl_xor(od[d], 1);
            od[d] += __shfl_xor(od[d], 2);
            od[d] *= rsum;   // all 4 lanes now hold the full O_h[t][0..23]
        }

        // ======== proj contribution: oacc[m] += sum_d O[d] * proj_w[c][h*24+d], c = g + 4*m
        #pragma unroll
        for (int m = 0; m < 24; ++m) {
            const int c = g + 4 * m;
            const float* wr = proj_w + c * 96 + h * 24;
            float s = 0.f;
            #pragma unroll
            for (int d4 = 0; d4 < 6; ++d4) {
                const float4 wv = *(const float4*)(wr + d4 * 4);
                s += od[d4 * 4 + 0] * wv.x + od[d4 * 4 + 1] * wv.y +
                     od[d4 * 4 + 2] * wv.z + od[d4 * 4 + 3] * wv.w;
            }
            oacc[m] += s;
        }
        __syncthreads();   // buf reused next head
    }

    // ---- stage outputs (stride 100) for coalesced stores
    #pragma unroll
    for (int m = 0; m < 24; ++m) {
        const int c = g + 4 * m;
        buf[t * XS_STRIDE + c] = oacc[m] + proj_b[c];
    }
    __syncthreads();

    for (int i = tid; i < 64 * 24; i += 256) {
        const int tt = i / 24;
        const int q4 = i - tt * 24;
        const int r  = tt >> 3, cc = tt & 7;
        *(float4*)(out + win_base + ((size_t)r * 256 + cc) * C96 + q4 * 4) =
            *(const float4*)&buf[tt * XS_STRIDE + q4 * 4];
    }
}

extern "C" void kernel_launch(void* const* d_in, const int* in_sizes, int n_in,
                              void* d_out, int out_size, void* d_ws, size_t ws_size,
                              hipStream_t stream) {
    const float* x      = (const float*)d_in[0];
    const float* qkv_w  = (const float*)d_in[1];
    const float* qkv_b  = (const float*)d_in[2];
    const float* proj_w = (const float*)d_in[3];
    const float* proj_b = (const float*)d_in[4];
    float* out = (float*)d_out;

    winattn_kernel<<<dim3(NWIN), dim3(256), 0, stream>>>(x, qkv_w, qkv_b, proj_w, proj_b, out);
}

// Round 2
// 243.112 us; speedup vs baseline: 34.0928x; 34.0928x over previous
//
#include <hip/hip_runtime.h>

// WindowAttention B=8 H=W=256 C=96 ws=8 heads=4 hd=24 — fp16 MFMA version.
// One block (256 thr = 4 waves) per window (8192 windows).

typedef _Float16 f16;
typedef f16 f16x8 __attribute__((ext_vector_type(8)));
typedef f16 f16x4 __attribute__((ext_vector_type(4)));
typedef float f32x4 __attribute__((ext_vector_type(4)));

#define MFMA16 __builtin_amdgcn_mfma_f32_16x16x32_f16

// XOR swizzle on f16 index: flips byte bits 4..6 -> spreads rows across 16B slots
__device__ __forceinline__ int swz(int idx, int row) { return idx ^ ((row & 7) << 3); }

__global__ void cvt_weights(const float* __restrict__ qkv_w,
                            const float* __restrict__ proj_w,
                            f16* __restrict__ ws) {
    int i = blockIdx.x * 256 + threadIdx.x;
    if (i < 27648)      ws[i] = (f16)qkv_w[i];
    else if (i < 36864) ws[i] = (f16)proj_w[i - 27648];
}

__global__ __launch_bounds__(256, 2) void winattn(
    const float* __restrict__ x,
    const f16*   __restrict__ qw,      // [288][96] fp16
    const float* __restrict__ qkv_b,   // [288]
    const f16*   __restrict__ pw,      // [96][96] fp16
    const float* __restrict__ proj_b,  // [96]
    float* __restrict__ out)
{
    __shared__ __align__(16) f16 xs[64*96 + 64];   // x window; reused as O
    __shared__ __align__(16) f16 qs[64*96 + 64];   // q [t][96] (+zeroed tail)
    __shared__ __align__(16) f16 ks[64*128];       // k [t][4 heads][32], d=24..31 zeroed
    __shared__ __align__(16) f16 vT[96*64 + 64];   // v transposed [ch][t]
    __shared__ __align__(16) f16 pl[4*16*64];      // per-wave P [16][64]

    const int tid = threadIdx.x;
    const int wid = blockIdx.x;
    const int bb = wid >> 10, wh = (wid >> 5) & 31, ww = wid & 31;
    const size_t win_base = ((size_t)(bb*256 + wh*8)*256 + (size_t)(ww*8)) * 96;

    const int lane = tid & 63, w = tid >> 6;
    const int lr = lane & 15, lg = lane >> 4;
    const int wm = w & 1, wn = w >> 1;

    // ---- entry zeroing: ks per-head K-pad (d=24..31), qs tail
    {
        const f16x8 z = {0,0,0,0,0,0,0,0};
        const int u = tid >> 2, h = tid & 3;
        *(f16x8*)&ks[swz(u*128 + h*32 + 24, u)] = z;
        if (tid < 8) *(f16x8*)&qs[6144 + tid*8] = z;
    }

    // ---- phase 0: stage x window -> fp16 LDS (swizzled)
    #pragma unroll
    for (int it = 0; it < 6; ++it) {
        const int f4i = it*256 + tid;           // 1536 float4s
        const int t = f4i / 24, c4 = f4i - t*24;
        const float4 v = *(const float4*)(x + win_base + (size_t)(((t>>3)<<8) + (t&7))*96 + c4*4);
        f16x4 h4 = {(f16)v.x, (f16)v.y, (f16)v.z, (f16)v.w};
        *(f16x4*)&xs[swz(t*96 + c4*4, t)] = h4;
    }
    __syncthreads();

    // ---- phase 1: QKV GEMM [64x96]@[96x288]  (wave = (wm,wn): 2 M-tiles x 9 N-tiles)
    {
        f16x8 a[2][3];
        #pragma unroll
        for (int mt = 0; mt < 2; ++mt)
            #pragma unroll
            for (int kk = 0; kk < 3; ++kk) {
                const int t = (wm*2 + mt)*16 + lr;
                a[mt][kk] = *(const f16x8*)&xs[swz(t*96 + kk*32 + lg*8, t)];
            }
        f32x4 acc[2][9];
        #pragma unroll
        for (int mt = 0; mt < 2; ++mt)
            #pragma unroll
            for (int n9 = 0; n9 < 9; ++n9) acc[mt][n9] = (f32x4){0.f,0.f,0.f,0.f};

        #pragma unroll
        for (int n9 = 0; n9 < 9; ++n9) {
            const int j = (wn*9 + n9)*16 + lr;
            #pragma unroll
            for (int kk = 0; kk < 3; ++kk) {
                const f16x8 bf = *(const f16x8*)(qw + j*96 + kk*32 + lg*8);
                acc[0][n9] = MFMA16(a[0][kk], bf, acc[0][n9], 0, 0, 0);
                acc[1][n9] = MFMA16(a[1][kk], bf, acc[1][n9], 0, 0, 0);
            }
        }
        // epilogue: +bias, fp16, scatter to qs/ks/vT
        #pragma unroll
        for (int n9 = 0; n9 < 9; ++n9) {
            const int n = wn*9 + n9;
            const int j = n*16 + lr;
            const float bias = qkv_b[j];
            #pragma unroll
            for (int mt = 0; mt < 2; ++mt) {
                const int t0 = (wm*2 + mt)*16 + lg*4;
                const f32x4 d = acc[mt][n9];
                if (n < 6) {                       // q: channel j
                    #pragma unroll
                    for (int r = 0; r < 4; ++r)
                        qs[swz((t0+r)*96 + j, t0+r)] = (f16)(d[r] + bias);
                } else if (n < 12) {               // k: head-padded layout
                    const int t1 = j - 96;
                    const int h = t1 / 24, dd = t1 - h*24;
                    #pragma unroll
                    for (int r = 0; r < 4; ++r)
                        ks[swz((t0+r)*128 + h*32 + dd, t0+r)] = (f16)(d[r] + bias);
                } else {                           // v: transposed
                    const int row = j - 192;
                    f16x4 vv = {(f16)(d[0]+bias), (f16)(d[1]+bias),
                                (f16)(d[2]+bias), (f16)(d[3]+bias)};
                    *(f16x4*)&vT[swz(row*64 + t0, row)] = vv;
                }
            }
        }
    }
    __syncthreads();

    // ---- phase 2: attention per head (wave w owns tokens 16w..16w+15)
    const float scale = 0.20412414523193154f;   // 24^-0.5
    for (int h = 0; h < 4; ++h) {
        const int tq = 16*w + lr;
        const f16x8 aq = *(const f16x8*)&qs[swz(tq*96 + h*24 + lg*8, tq)];
        f32x4 s[4];
        #pragma unroll
        for (int n = 0; n < 4; ++n) {
            const int u = 16*n + lr;
            const f16x8 bk = *(const f16x8*)&ks[swz(u*128 + h*32 + lg*8, u)];
            s[n] = MFMA16(aq, bk, (f32x4){0.f,0.f,0.f,0.f}, 0, 0, 0);
        }
        float p[4][4], mx[4], sm[4], rs[4];
        #pragma unroll
        for (int r = 0; r < 4; ++r) mx[r] = -1e30f;
        #pragma unroll
        for (int n = 0; n < 4; ++n)
            #pragma unroll
            for (int r = 0; r < 4; ++r) {
                p[n][r] = s[n][r] * scale;
                mx[r] = fmaxf(mx[r], p[n][r]);
            }
        #pragma unroll
        for (int r = 0; r < 4; ++r) {
            mx[r] = fmaxf(mx[r], __shfl_xor(mx[r], 1));
            mx[r] = fmaxf(mx[r], __shfl_xor(mx[r], 2));
            mx[r] = fmaxf(mx[r], __shfl_xor(mx[r], 4));
            mx[r] = fmaxf(mx[r], __shfl_xor(mx[r], 8));
            sm[r] = 0.f;
        }
        #pragma unroll
        for (int n = 0; n < 4; ++n)
            #pragma unroll
            for (int r = 0; r < 4; ++r) {
                p[n][r] = __expf(p[n][r] - mx[r]);
                sm[r] += p[n][r];
            }
        #pragma unroll
        for (int r = 0; r < 4; ++r) {
            sm[r] += __shfl_xor(sm[r], 1);
            sm[r] += __shfl_xor(sm[r], 2);
            sm[r] += __shfl_xor(sm[r], 4);
            sm[r] += __shfl_xor(sm[r], 8);
            rs[r] = 1.f / sm[r];
        }
        // write unnormalized P (<=1) to wave-private LDS
        #pragma unroll
        for (int n = 0; n < 4; ++n)
            #pragma unroll
            for (int r = 0; r < 4; ++r) {
                const int tr = lg*4 + r;
                pl[swz(w*1024 + tr*64 + 16*n + lr, tr)] = (f16)p[n][r];
            }
        // PV: O[16x24] = P[16x64] @ V[64x24]  (2 K-steps, 2 N-tiles, col>=24 discarded)
        f32x4 o0 = {0.f,0.f,0.f,0.f}, o1 = {0.f,0.f,0.f,0.f};
        const int d1e = (16 + lr > 23) ? 23 : 16 + lr;   // clamp keeps addr valid
        #pragma unroll
        for (int kk = 0; kk < 2; ++kk) {
            const f16x8 ap = *(const f16x8*)&pl[swz(w*1024 + lr*64 + kk*32 + lg*8, lr)];
            const int r0 = h*24 + lr;
            const f16x8 b0 = *(const f16x8*)&vT[swz(r0*64 + kk*32 + lg*8, r0)];
            o0 = MFMA16(ap, b0, o0, 0, 0, 0);
            const int r1 = h*24 + d1e;
            const f16x8 b1 = *(const f16x8*)&vT[swz(r1*64 + kk*32 + lg*8, r1)];
            o1 = MFMA16(ap, b1, o1, 0, 0, 0);
        }
        #pragma unroll
        for (int r = 0; r < 4; ++r) {
            const int t = 16*w + lg*4 + r;
            xs[swz(t*96 + h*24 + lr, t)] = (f16)(o0[r] * rs[r]);
            if (lr < 8)
                xs[swz(t*96 + h*24 + 16 + lr, t)] = (f16)(o1[r] * rs[r]);
        }
    }
    __syncthreads();

    // ---- phase 3: proj [64x96]@[96x96] + bias, store fp32
    {
        f16x8 ao[2][3];
        #pragma unroll
        for (int mt = 0; mt < 2; ++mt)
            #pragma unroll
            for (int kk = 0; kk < 3; ++kk) {
                const int t = (wm*2 + mt)*16 + lr;
                ao[mt][kk] = *(const f16x8*)&xs[swz(t*96 + kk*32 + lg*8, t)];
            }
        #pragma unroll
        for (int n3 = 0; n3 < 3; ++n3) {
            const int c = (wn*3 + n3)*16 + lr;
            f32x4 pa0 = {0.f,0.f,0.f,0.f}, pa1 = {0.f,0.f,0.f,0.f};
            #pragma unroll
            for (int kk = 0; kk < 3; ++kk) {
                const f16x8 bw = *(const f16x8*)(pw + c*96 + kk*32 + lg*8);
                pa0 = MFMA16(ao[0][kk], bw, pa0, 0, 0, 0);
                pa1 = MFMA16(ao[1][kk], bw, pa1, 0, 0, 0);
            }
            const float pb = proj_b[c];
            #pragma unroll
            for (int r = 0; r < 4; ++r) {
                int t = (wm*2 + 0)*16 + lg*4 + r;
                out[win_base + (size_t)(((t>>3)<<8) + (t&7))*96 + c] = pa0[r] + pb;
                t = (wm*2 + 1)*16 + lg*4 + r;
                out[win_base + (size_t)(((t>>3)<<8) + (t&7))*96 + c] = pa1[r] + pb;
            }
        }
    }
}

extern "C" void kernel_launch(void* const* d_in, const int* in_sizes, int n_in,
                              void* d_out, int out_size, void* d_ws, size_t ws_size,
                              hipStream_t stream) {
    const float* x      = (const float*)d_in[0];
    const float* qkv_w  = (const float*)d_in[1];
    const float* qkv_b  = (const float*)d_in[2];
    const float* proj_w = (const float*)d_in[3];
    const float* proj_b = (const float*)d_in[4];
    float* out = (float*)d_out;
    f16* ws = (f16*)d_ws;   // qw[27648] then pw[9216] fp16

    cvt_weights<<<dim3(144), dim3(256), 0, stream>>>(qkv_w, proj_w, ws);
    winattn<<<dim3(8192), dim3(256), 0, stream>>>(x, ws, qkv_b, ws + 27648, proj_b, out);
}